// Round 4
// baseline (3555.244 us; speedup 1.0000x reference)
//
#include <hip/hip_runtime.h>
#include <math.h>

#define B_  2048
#define I_  512
#define H_  512
#define L_  32
#define D_  1024
#define O_  512
#define H4_ 2048
#define KC  32

typedef _Float16 f16x8 __attribute__((ext_vector_type(8)));
typedef _Float16 f16x4 __attribute__((ext_vector_type(4)));
typedef float    f32x4 __attribute__((ext_vector_type(4)));

#define SPLIT_S  1024.0f
#define SPLIT_RS 0.0009765625f   /* 1/1024 */

// async global->LDS, 16B per lane; LDS dest = wave-uniform base + lane*16
__device__ __forceinline__ void gload16(const _Float16* g, _Float16* l) {
    __builtin_amdgcn_global_load_lds(
        (const __attribute__((address_space(1))) void*)g,
        (__attribute__((address_space(3))) void*)l, 16, 0, 0);
}

// swizzled fragment read: LDS chunk c holds global chunk c^(row&7)
__device__ __forceinline__ f16x8 lds_frag(const _Float16* base, int row, int ko) {
    int off = row * 64 + ((((ko >> 3) ^ (row & 7))) << 3);
    return *(const f16x8*)(base + off);
}

// ---------------------------------------------------------------------------
// Generic fp32 GEMM (kept for one-time GEMMs: cx0, P_enc, P_dec, recon).
// ---------------------------------------------------------------------------
__global__ __launch_bounds__(256) void gemm_atb(
    const float* __restrict__ A, const float* __restrict__ W,
    const float* __restrict__ bias, float* __restrict__ C, int ldc,
    float* __restrict__ C2, int ldc2,
    int M, int N, int K)
{
    __shared__ __align__(16) float As[KC][68];
    __shared__ __align__(16) float Ws[KC][68];
    const int tx = threadIdx.x & 15, ty = threadIdx.x >> 4;
    const int m0 = blockIdx.y * 64, n0 = blockIdx.x * 64;
    float acc[4][4] = {};

    for (int k0 = 0; k0 < K; k0 += KC) {
#pragma unroll
        for (int p = 0; p < 2; ++p) {
            int q = threadIdx.x + 256 * p;
            int r = q >> 3, c = q & 7;
            float4 va = *reinterpret_cast<const float4*>(
                &A[(long long)(m0 + r) * K + k0 + c * 4]);
            As[c * 4 + 0][r] = va.x; As[c * 4 + 1][r] = va.y;
            As[c * 4 + 2][r] = va.z; As[c * 4 + 3][r] = va.w;
            float4 vw = *reinterpret_cast<const float4*>(
                &W[(long long)(n0 + r) * K + k0 + c * 4]);
            Ws[c * 4 + 0][r] = vw.x; Ws[c * 4 + 1][r] = vw.y;
            Ws[c * 4 + 2][r] = vw.z; Ws[c * 4 + 3][r] = vw.w;
        }
        __syncthreads();
#pragma unroll
        for (int kk = 0; kk < KC; ++kk) {
            float4 a = *reinterpret_cast<const float4*>(&As[kk][ty * 4]);
            float4 w = *reinterpret_cast<const float4*>(&Ws[kk][tx * 4]);
            float av[4] = {a.x, a.y, a.z, a.w};
            float wv[4] = {w.x, w.y, w.z, w.w};
#pragma unroll
            for (int i = 0; i < 4; ++i)
#pragma unroll
                for (int j = 0; j < 4; ++j)
                    acc[i][j] = fmaf(av[i], wv[j], acc[i][j]);
        }
        __syncthreads();
    }

#pragma unroll
    for (int i = 0; i < 4; ++i) {
        int m = m0 + ty * 4 + i;
        int n = n0 + tx * 4;
        float4 out;
        out.x = acc[i][0]; out.y = acc[i][1]; out.z = acc[i][2]; out.w = acc[i][3];
        if (bias) {
            out.x += bias[n + 0]; out.y += bias[n + 1];
            out.z += bias[n + 2]; out.w += bias[n + 3];
        }
        *reinterpret_cast<float4*>(&C[(long long)m * ldc + n]) = out;
        if (C2)
            *reinterpret_cast<float4*>(&C2[(long long)m * ldc2 + n]) = out;
    }
}

// ---------------------------------------------------------------------------
// Split fp32 -> scaled fp16 pair:  x ~= x1 + x2/1024  (error ~2^-22 |x|).
// ---------------------------------------------------------------------------
__global__ __launch_bounds__(256) void split_f16(
    const float* __restrict__ src, _Float16* __restrict__ d1,
    _Float16* __restrict__ d2, int n4)
{
    int i = blockIdx.x * 256 + threadIdx.x;
    if (i >= n4) return;
    float4 v = reinterpret_cast<const float4*>(src)[i];
    float vv[4] = {v.x, v.y, v.z, v.w};
    f16x4 o1, o2;
#pragma unroll
    for (int j = 0; j < 4; ++j) {
        _Float16 hh = (_Float16)vv[j];
        o1[j] = hh;
        o2[j] = (_Float16)((vv[j] - (float)hh) * SPLIT_S);
    }
    *reinterpret_cast<f16x4*>(d1 + 4 * i) = o1;
    *reinterpret_cast<f16x4*>(d2 + 4 * i) = o2;
}

// ---------------------------------------------------------------------------
// Fused MFMA LSTM step, DOUBLE-BUFFERED prefetch:
//   prologue stages tile0; each K-iter issues next-tile global_load_lds
//   FIRST, then computes current tile, then one __syncthreads (drains the
//   prefetch whose latency hid under the MFMAs).  128 KB LDS, 1 block/CU.
// ---------------------------------------------------------------------------
__global__ __launch_bounds__(512) void lstm_step_mfma(
    const _Float16* __restrict__ hx1, const _Float16* __restrict__ hx2,
    float* __restrict__ cx,
    const _Float16* __restrict__ W1, const _Float16* __restrict__ W2, // [4H][H]
    const float* __restrict__ P,      // [D][4H] gather table (fp32)
    const int* __restrict__ m_prev,   // [B] or nullptr
    const float* __restrict__ bih, const float* __restrict__ bhh,
    _Float16* __restrict__ ho1, _Float16* __restrict__ ho2,
    float* __restrict__ hof)          // fp32 hx out (nullptr to skip)
{
    __shared__ __align__(16) _Float16 As1[2][128 * 64];
    __shared__ __align__(16) _Float16 As2[2][128 * 64];
    __shared__ __align__(16) _Float16 Ws1[2][128 * 64];
    __shared__ __align__(16) _Float16 Ws2[2][128 * 64];
    __shared__ int ms[128];

    const int tid = threadIdx.x;
    const int m0 = blockIdx.y * 128, h0 = blockIdx.x * 32;
    const int ln = tid & 63, wid = tid >> 6;
    const int wm = wid >> 1, wn = wid & 1;

    if (m_prev != nullptr && tid < 128) ms[tid] = m_prev[m0 + tid];

    f32x4 accM[2][4] = {};
    f32x4 accC[2][4] = {};

    // stage tile (k0) into buffer buf: each wave owns segments wid, wid+8
    auto stage = [&](int buf, int k0) {
#pragma unroll
        for (int s = 0; s < 2; ++s) {
            int seg = wid + s * 8;
            int r   = seg * 8 + (ln >> 3);
            int jsw = ((ln & 7) ^ (ln >> 3)) << 3;
            size_t ga = (size_t)(m0 + r) * H_ + k0 + jsw;
            gload16(hx1 + ga, &As1[buf][seg * 512]);
            gload16(hx2 + ga, &As2[buf][seg * 512]);
            int wrow = ((r >> 4) & 3) * H_ + h0 + ((r >> 6) << 4) + (r & 15);
            size_t gw = (size_t)wrow * H_ + k0 + jsw;
            gload16(W1 + gw, &Ws1[buf][seg * 512]);
            gload16(W2 + gw, &Ws2[buf][seg * 512]);
        }
    };

    stage(0, 0);
    __syncthreads();

    const int ac = (ln >> 4) << 3;
    const int arow = wm * 32 + (ln & 15);
    const int brow = wn * 64 + (ln & 15);
    int cur = 0;

    for (int t = 0; t < 8; ++t) {
        if (t < 7) stage(cur ^ 1, (t + 1) * 64);   // prefetch next tile
        const _Float16* a1b = &As1[cur][0];
        const _Float16* a2b = &As2[cur][0];
        const _Float16* w1b = &Ws1[cur][0];
        const _Float16* w2b = &Ws2[cur][0];
#pragma unroll
        for (int kc = 0; kc < 2; ++kc) {
            int ko = kc * 32 + ac;
            f16x8 b1[4], b2[4];
#pragma unroll
            for (int fn = 0; fn < 4; ++fn) {
                b1[fn] = lds_frag(w1b, brow + fn * 16, ko);
                b2[fn] = lds_frag(w2b, brow + fn * 16, ko);
            }
#pragma unroll
            for (int fm = 0; fm < 2; ++fm) {
                f16x8 a1 = lds_frag(a1b, arow + fm * 16, ko);
                f16x8 a2 = lds_frag(a2b, arow + fm * 16, ko);
#pragma unroll
                for (int fn = 0; fn < 4; ++fn) {
                    accM[fm][fn] = __builtin_amdgcn_mfma_f32_16x16x32_f16(
                        a1, b1[fn], accM[fm][fn], 0, 0, 0);
                    accC[fm][fn] = __builtin_amdgcn_mfma_f32_16x16x32_f16(
                        a1, b2[fn], accC[fm][fn], 0, 0, 0);
                    accC[fm][fn] = __builtin_amdgcn_mfma_f32_16x16x32_f16(
                        a2, b1[fn], accC[fm][fn], 0, 0, 0);
                }
            }
        }
        __syncthreads();       // drains prefetch vmcnt + protects buffer swap
        cur ^= 1;
    }

    // ---- epilogue: each lane owns (h, all 4 gates) for 8 batch rows ----
    const int hl = ln & 15;
    const int h  = h0 + wn * 16 + hl;
    const int rb = m0 + wm * 32 + ((ln >> 4) << 2);
    float bs0 = bih[0 * H_ + h] + bhh[0 * H_ + h];
    float bs1 = bih[1 * H_ + h] + bhh[1 * H_ + h];
    float bs2 = bih[2 * H_ + h] + bhh[2 * H_ + h];
    float bs3 = bih[3 * H_ + h] + bhh[3 * H_ + h];
#pragma unroll
    for (int fm = 0; fm < 2; ++fm) {
#pragma unroll
        for (int rg = 0; rg < 4; ++rg) {
            int b = rb + fm * 16 + rg;
            float g0 = accM[fm][0][rg] + SPLIT_RS * accC[fm][0][rg] + bs0;
            float g1 = accM[fm][1][rg] + SPLIT_RS * accC[fm][1][rg] + bs1;
            float g2 = accM[fm][2][rg] + SPLIT_RS * accC[fm][2][rg] + bs2;
            float g3 = accM[fm][3][rg] + SPLIT_RS * accC[fm][3][rg] + bs3;
            if (m_prev != nullptr) {
                const float* Pr = P + (size_t)ms[b - m0] * H4_;
                g0 += Pr[0 * H_ + h]; g1 += Pr[1 * H_ + h];
                g2 += Pr[2 * H_ + h]; g3 += Pr[3 * H_ + h];
            }
            float ig = 1.f / (1.f + expf(-g0));
            float fg = 1.f / (1.f + expf(-g1));
            float gg = tanhf(g2);
            float og = 1.f / (1.f + expf(-g3));
            size_t off = (size_t)b * H_ + h;
            float cnew = fg * cx[off] + ig * gg;
            cx[off] = cnew;
            float hv = og * tanhf(cnew);
            _Float16 hh1 = (_Float16)hv;
            ho1[off] = hh1;
            ho2[off] = (_Float16)((hv - (float)hh1) * SPLIT_S);
            if (hof != nullptr) hof[off] = hv;
        }
    }
}

// ---------------------------------------------------------------------------
// MFMA pre-GEMM, double-buffered, with fused argmax partials AND the final
// 8-partial reduce done by the last-arriving block of each row group
// (threadfence + atomic counter; replaces the argmax_fin kernel).
// ---------------------------------------------------------------------------
__global__ __launch_bounds__(256) void gemm_pre_fused(
    const _Float16* __restrict__ A1, const _Float16* __restrict__ A2, // [B][H]
    const _Float16* __restrict__ W1, const _Float16* __restrict__ W2, // [D][H]
    const float* __restrict__ bias,
    float* __restrict__ C2, int ldc2,   // logits slice (offset by l*D)
    const float* __restrict__ gum,      // gumbel + l*B*D  -> [B][D]
    float* __restrict__ pbest, int* __restrict__ pidx,  // [B][8]
    int* __restrict__ cnt,              // [gridDim.y] counters for step l
    float* __restrict__ onehot, float* __restrict__ messages,
    int* __restrict__ m_out, int l)
{
    __shared__ __align__(16) _Float16 As1[2][64 * 64];
    __shared__ __align__(16) _Float16 As2[2][64 * 64];
    __shared__ __align__(16) _Float16 Ws1[2][128 * 64];
    __shared__ __align__(16) _Float16 Ws2[2][128 * 64];
    __shared__ float cb[2][64];
    __shared__ int   ci[2][64];
    __shared__ int   lastf;

    const int tid = threadIdx.x;
    const int m0 = blockIdx.y * 64, n0 = blockIdx.x * 128;
    const int ln = tid & 63, wid = tid >> 6;
    const int wm = wid >> 1, wn = wid & 1;

    f32x4 accM[2][4] = {};
    f32x4 accC[2][4] = {};

    auto stage = [&](int buf, int k0) {
#pragma unroll
        for (int s = 0; s < 2; ++s) {           // A: 8 segments over 4 waves
            int seg = wid + s * 4;
            int r   = seg * 8 + (ln >> 3);
            int jsw = ((ln & 7) ^ (ln >> 3)) << 3;
            size_t ga = (size_t)(m0 + r) * H_ + k0 + jsw;
            gload16(A1 + ga, &As1[buf][seg * 512]);
            gload16(A2 + ga, &As2[buf][seg * 512]);
        }
#pragma unroll
        for (int s = 0; s < 4; ++s) {           // W: 16 segments over 4 waves
            int seg = wid + s * 4;
            int r   = seg * 8 + (ln >> 3);
            int jsw = ((ln & 7) ^ (ln >> 3)) << 3;
            size_t gw = (size_t)(n0 + r) * H_ + k0 + jsw;
            gload16(W1 + gw, &Ws1[buf][seg * 512]);
            gload16(W2 + gw, &Ws2[buf][seg * 512]);
        }
    };

    stage(0, 0);
    __syncthreads();

    const int ac = (ln >> 4) << 3;
    const int arow = wm * 32 + (ln & 15);
    const int brow = wn * 64 + (ln & 15);
    int cur = 0;

    for (int t = 0; t < 8; ++t) {
        if (t < 7) stage(cur ^ 1, (t + 1) * 64);
        const _Float16* a1b = &As1[cur][0];
        const _Float16* a2b = &As2[cur][0];
        const _Float16* w1b = &Ws1[cur][0];
        const _Float16* w2b = &Ws2[cur][0];
#pragma unroll
        for (int kc = 0; kc < 2; ++kc) {
            int ko = kc * 32 + ac;
            f16x8 b1[4], b2[4];
#pragma unroll
            for (int fn = 0; fn < 4; ++fn) {
                b1[fn] = lds_frag(w1b, brow + fn * 16, ko);
                b2[fn] = lds_frag(w2b, brow + fn * 16, ko);
            }
#pragma unroll
            for (int fm = 0; fm < 2; ++fm) {
                f16x8 a1 = lds_frag(a1b, arow + fm * 16, ko);
                f16x8 a2 = lds_frag(a2b, arow + fm * 16, ko);
#pragma unroll
                for (int fn = 0; fn < 4; ++fn) {
                    accM[fm][fn] = __builtin_amdgcn_mfma_f32_16x16x32_f16(
                        a1, b1[fn], accM[fm][fn], 0, 0, 0);
                    accC[fm][fn] = __builtin_amdgcn_mfma_f32_16x16x32_f16(
                        a1, b2[fn], accC[fm][fn], 0, 0, 0);
                    accC[fm][fn] = __builtin_amdgcn_mfma_f32_16x16x32_f16(
                        a2, b1[fn], accC[fm][fn], 0, 0, 0);
                }
            }
        }
        __syncthreads();
        cur ^= 1;
    }

    // ---- epilogue: write logits; fold gumbel; per-block argmax partial ----
    const int hl = ln & 15;
    const int g4 = ln >> 4;
    const int rb = m0 + wm * 32 + (g4 << 2);
    float vbest[2][4]; int vidx[2][4];
#pragma unroll
    for (int fm = 0; fm < 2; ++fm)
#pragma unroll
        for (int rg = 0; rg < 4; ++rg) { vbest[fm][rg] = -INFINITY; vidx[fm][rg] = 0; }

#pragma unroll
    for (int fn = 0; fn < 4; ++fn) {
        int d = n0 + wn * 64 + fn * 16 + hl;
        float bv = bias[d];
#pragma unroll
        for (int fm = 0; fm < 2; ++fm)
#pragma unroll
            for (int rg = 0; rg < 4; ++rg) {
                int b = rb + fm * 16 + rg;
                float v = accM[fm][fn][rg] + SPLIT_RS * accC[fm][fn][rg] + bv;
                C2[(size_t)b * ldc2 + d] = v;
                float t = v + gum[(size_t)b * D_ + d];
                if (t > vbest[fm][rg]) { vbest[fm][rg] = t; vidx[fm][rg] = d; }
            }
    }

    // butterfly over the 16 hl lanes (d ascending with fn; ties keep low d)
#pragma unroll
    for (int off = 1; off < 16; off <<= 1) {
#pragma unroll
        for (int fm = 0; fm < 2; ++fm)
#pragma unroll
            for (int rg = 0; rg < 4; ++rg) {
                float ov = __shfl_xor(vbest[fm][rg], off);
                int   oi = __shfl_xor(vidx[fm][rg], off);
                if (ov > vbest[fm][rg] ||
                    (ov == vbest[fm][rg] && oi < vidx[fm][rg])) {
                    vbest[fm][rg] = ov; vidx[fm][rg] = oi;
                }
            }
    }
    if (hl == 0) {
#pragma unroll
        for (int fm = 0; fm < 2; ++fm)
#pragma unroll
            for (int rg = 0; rg < 4; ++rg) {
                int rl = wm * 32 + fm * 16 + (g4 << 2) + rg;
                cb[wn][rl] = vbest[fm][rg];
                ci[wn][rl] = vidx[fm][rg];
            }
    }
    __syncthreads();
    if (tid < 64) {
        float b0 = cb[0][tid]; int i0 = ci[0][tid];
        float b1v = cb[1][tid]; int i1 = ci[1][tid];
        if (b1v > b0 || (b1v == b0 && i1 < i0)) { b0 = b1v; i0 = i1; }
        pbest[(size_t)(m0 + tid) * 8 + blockIdx.x] = b0;
        pidx [(size_t)(m0 + tid) * 8 + blockIdx.x] = i0;
        __threadfence();                 // make this block's partials visible
    }
    __syncthreads();
    if (tid == 0)
        lastf = (atomicAdd(cnt + blockIdx.y, 1) == 7);
    __syncthreads();
    if (lastf) {                         // last block of this row group
        __threadfence();                 // acquire: see other blocks' partials
        if (tid < 64) {
            int b = m0 + tid;
            volatile const float* pb = pbest + (size_t)b * 8;
            volatile const int*   pi = pidx  + (size_t)b * 8;
            float best = -INFINITY; int bi = 0;
#pragma unroll
            for (int j = 0; j < 8; ++j) {
                float v = pb[j]; int i = pi[j];
                if (v > best || (v == best && i < bi)) { best = v; bi = i; }
            }
            m_out[b] = bi;
            messages[(size_t)b * L_ + l] = (float)bi;
            onehot[((size_t)b * L_ + l) * D_ + bi] = 1.0f;
        }
    }
}

// t2h_emb[d, h] = t2h_W[h, d] + t2h_b[h]
__global__ __launch_bounds__(256) void build_emb(
    const float* __restrict__ t2h_W, const float* __restrict__ t2h_b,
    float* __restrict__ emb)
{
    int idx = blockIdx.x * 256 + threadIdx.x;
    int d = idx >> 9, h = idx & (H_ - 1);
    emb[idx] = t2h_W[(long long)h * D_ + d] + t2h_b[h];
}

// ---------------------------------------------------------------------------
extern "C" void kernel_launch(void* const* d_in, const int* in_sizes, int n_in,
                              void* d_out, int out_size, void* d_ws, size_t ws_size,
                              hipStream_t stream)
{
    (void)in_sizes; (void)n_in; (void)out_size; (void)ws_size;
    const float* x       = (const float*)d_in[0];
    const float* gumbel  = (const float*)d_in[1];
    const float* in_W    = (const float*)d_in[2];
    const float* in_b    = (const float*)d_in[3];
    const float* out_W   = (const float*)d_in[4];
    const float* out_b   = (const float*)d_in[5];
    const float* enc_Wih = (const float*)d_in[6];
    const float* enc_Whh = (const float*)d_in[7];
    const float* enc_bih = (const float*)d_in[8];
    const float* enc_bhh = (const float*)d_in[9];
    const float* dec_Wih = (const float*)d_in[10];
    const float* dec_Whh = (const float*)d_in[11];
    const float* dec_bih = (const float*)d_in[12];
    const float* dec_bhh = (const float*)d_in[13];
    const float* h2t_W   = (const float*)d_in[14];
    const float* h2t_b   = (const float*)d_in[15];
    const float* t2h_W   = (const float*)d_in[16];
    const float* t2h_b   = (const float*)d_in[17];

    float* out      = (float*)d_out;
    float* recon    = out;                                  // [B,O]
    float* onehot   = out + (size_t)B_ * O_;                // [B,L,D]
    float* logits   = onehot + (size_t)B_ * L_ * D_;        // [B,L,D]
    float* messages = logits + (size_t)B_ * L_ * D_;        // [B,L]

    float* ws    = (float*)d_ws;
    float* cx    = ws;                                      // [B,H]
    float* emb   = cx + (size_t)B_ * H_;                    // [D,H]
    float* P_enc = emb + (size_t)D_ * H_;                   // [D,4H]
    float* P_dec = P_enc + (size_t)D_ * H4_;                // [D,4H]
    float* hxf   = P_dec + (size_t)D_ * H4_;                // [B,H]
    float* pbest = hxf + (size_t)B_ * H_;                   // [B,8]
    int*   pidx  = (int*)(pbest + (size_t)B_ * 8);          // [B,8]
    int*   m_all = pidx + (size_t)B_ * 8;                   // [L,B]
    int*   cnt   = m_all + (size_t)L_ * B_;                 // [L,32]
    _Float16* fb   = (_Float16*)(cnt + L_ * 32);
    _Float16* hxA1 = fb;  fb += (size_t)B_ * H_;
    _Float16* hxA2 = fb;  fb += (size_t)B_ * H_;
    _Float16* hxB1 = fb;  fb += (size_t)B_ * H_;
    _Float16* hxB2 = fb;  fb += (size_t)B_ * H_;
    _Float16* encW1 = fb; fb += (size_t)H4_ * H_;
    _Float16* encW2 = fb; fb += (size_t)H4_ * H_;
    _Float16* decW1 = fb; fb += (size_t)H4_ * H_;
    _Float16* decW2 = fb; fb += (size_t)H4_ * H_;
    _Float16* h2t1  = fb; fb += (size_t)D_ * H_;
    _Float16* h2t2  = fb;

    const dim3 blk256(256);

    (void)hipMemsetAsync(hxA1, 0, (size_t)B_ * H_ * 4, stream);
    (void)hipMemsetAsync(onehot, 0, (size_t)B_ * L_ * D_ * sizeof(float), stream);
    (void)hipMemsetAsync(cnt, 0, (size_t)L_ * 32 * sizeof(int), stream);

    // weight splits (one-time)
    split_f16<<<dim3((H4_ * H_ / 4) / 256), blk256, 0, stream>>>(
        enc_Whh, encW1, encW2, H4_ * H_ / 4);
    split_f16<<<dim3((H4_ * H_ / 4) / 256), blk256, 0, stream>>>(
        dec_Whh, decW1, decW2, H4_ * H_ / 4);
    split_f16<<<dim3((D_ * H_ / 4) / 256), blk256, 0, stream>>>(
        h2t_W, h2t1, h2t2, D_ * H_ / 4);

    // cx0 (encoder initial cell state) = x @ in_W^T + in_b  (fp32)
    gemm_atb<<<dim3(H_ / 64, B_ / 64), blk256, 0, stream>>>(
        x, in_W, in_b, cx, H_, nullptr, 0, B_, H_, I_);

    // one-hot decode table and the two precomputed gather tables (fp32)
    build_emb<<<dim3((D_ * H_) / 256), blk256, 0, stream>>>(t2h_W, t2h_b, emb);
    gemm_atb<<<dim3(H4_ / 64, D_ / 64), blk256, 0, stream>>>(
        emb, enc_Wih, nullptr, P_enc, H4_, nullptr, 0, D_, H4_, H_);
    gemm_atb<<<dim3(H4_ / 64, D_ / 64), blk256, 0, stream>>>(
        emb, dec_Wih, nullptr, P_dec, H4_, nullptr, 0, D_, H4_, H_);

    // ---------------- encoder ----------------
    _Float16 *c1 = hxA1, *c2 = hxA2, *n1 = hxB1, *n2 = hxB2;
    for (int l = 0; l < L_; ++l) {
        lstm_step_mfma<<<dim3(H_ / 32, B_ / 128), dim3(512), 0, stream>>>(
            c1, c2, cx, encW1, encW2, P_enc,
            (l == 0) ? nullptr : (m_all + (size_t)(l - 1) * B_),
            enc_bih, enc_bhh, n1, n2, nullptr);
        { _Float16* t = c1; c1 = n1; n1 = t; t = c2; c2 = n2; n2 = t; }
        gemm_pre_fused<<<dim3(D_ / 128, B_ / 64), blk256, 0, stream>>>(
            c1, c2, h2t1, h2t2, h2t_b,
            logits + (size_t)l * D_, L_ * D_,
            gumbel + (size_t)l * B_ * D_, pbest, pidx,
            cnt + l * 32, onehot, messages, m_all + (size_t)l * B_, l);
    }

    // ---------------- decoder ----------------
    (void)hipMemsetAsync(c1, 0, (size_t)B_ * H_ * 2, stream);
    (void)hipMemsetAsync(c2, 0, (size_t)B_ * H_ * 2, stream);
    (void)hipMemsetAsync(cx, 0, (size_t)B_ * H_ * sizeof(float), stream);
    for (int l = 0; l < L_; ++l) {
        lstm_step_mfma<<<dim3(H_ / 32, B_ / 128), dim3(512), 0, stream>>>(
            c1, c2, cx, decW1, decW2, P_dec, m_all + (size_t)l * B_,
            dec_bih, dec_bhh, n1, n2, (l == L_ - 1) ? hxf : nullptr);
        { _Float16* t = c1; c1 = n1; n1 = t; t = c2; c2 = n2; n2 = t; }
    }

    // recon = hx_final @ out_W^T + out_b  (fp32)
    gemm_atb<<<dim3(O_ / 64, B_ / 64), blk256, 0, stream>>>(
        hxf, out_W, out_b, recon, O_, nullptr, 0, B_, O_, H_);
}

// Round 5
// 2873.094 us; speedup vs baseline: 1.2374x; 1.2374x over previous
//
#include <hip/hip_runtime.h>
#include <math.h>

#define B_  2048
#define I_  512
#define H_  512
#define L_  32
#define D_  1024
#define O_  512
#define H4_ 2048
#define KC  32

typedef _Float16 f16x8 __attribute__((ext_vector_type(8)));
typedef _Float16 f16x4 __attribute__((ext_vector_type(4)));
typedef float    f32x4 __attribute__((ext_vector_type(4)));

#define SPLIT_S  1024.0f
#define SPLIT_RS 0.0009765625f   /* 1/1024 */

// async global->LDS, 16B per lane; LDS dest = wave-uniform base + lane*16
__device__ __forceinline__ void gload16(const _Float16* g, _Float16* l) {
    __builtin_amdgcn_global_load_lds(
        (const __attribute__((address_space(1))) void*)g,
        (__attribute__((address_space(3))) void*)l, 16, 0, 0);
}

// swizzled fragment read: LDS chunk c holds global chunk c^(row&7)
__device__ __forceinline__ f16x8 lds_frag(const _Float16* base, int row, int ko) {
    int off = row * 64 + ((((ko >> 3) ^ (row & 7))) << 3);
    return *(const f16x8*)(base + off);
}

// ---------------------------------------------------------------------------
// Generic fp32 GEMM (kept for one-time GEMMs: cx0, P_enc, P_dec, recon).
// ---------------------------------------------------------------------------
__global__ __launch_bounds__(256) void gemm_atb(
    const float* __restrict__ A, const float* __restrict__ W,
    const float* __restrict__ bias, float* __restrict__ C, int ldc,
    float* __restrict__ C2, int ldc2,
    int M, int N, int K)
{
    __shared__ __align__(16) float As[KC][68];
    __shared__ __align__(16) float Ws[KC][68];
    const int tx = threadIdx.x & 15, ty = threadIdx.x >> 4;
    const int m0 = blockIdx.y * 64, n0 = blockIdx.x * 64;
    float acc[4][4] = {};

    for (int k0 = 0; k0 < K; k0 += KC) {
#pragma unroll
        for (int p = 0; p < 2; ++p) {
            int q = threadIdx.x + 256 * p;
            int r = q >> 3, c = q & 7;
            float4 va = *reinterpret_cast<const float4*>(
                &A[(long long)(m0 + r) * K + k0 + c * 4]);
            As[c * 4 + 0][r] = va.x; As[c * 4 + 1][r] = va.y;
            As[c * 4 + 2][r] = va.z; As[c * 4 + 3][r] = va.w;
            float4 vw = *reinterpret_cast<const float4*>(
                &W[(long long)(n0 + r) * K + k0 + c * 4]);
            Ws[c * 4 + 0][r] = vw.x; Ws[c * 4 + 1][r] = vw.y;
            Ws[c * 4 + 2][r] = vw.z; Ws[c * 4 + 3][r] = vw.w;
        }
        __syncthreads();
#pragma unroll
        for (int kk = 0; kk < KC; ++kk) {
            float4 a = *reinterpret_cast<const float4*>(&As[kk][ty * 4]);
            float4 w = *reinterpret_cast<const float4*>(&Ws[kk][tx * 4]);
            float av[4] = {a.x, a.y, a.z, a.w};
            float wv[4] = {w.x, w.y, w.z, w.w};
#pragma unroll
            for (int i = 0; i < 4; ++i)
#pragma unroll
                for (int j = 0; j < 4; ++j)
                    acc[i][j] = fmaf(av[i], wv[j], acc[i][j]);
        }
        __syncthreads();
    }

#pragma unroll
    for (int i = 0; i < 4; ++i) {
        int m = m0 + ty * 4 + i;
        int n = n0 + tx * 4;
        float4 out;
        out.x = acc[i][0]; out.y = acc[i][1]; out.z = acc[i][2]; out.w = acc[i][3];
        if (bias) {
            out.x += bias[n + 0]; out.y += bias[n + 1];
            out.z += bias[n + 2]; out.w += bias[n + 3];
        }
        *reinterpret_cast<float4*>(&C[(long long)m * ldc + n]) = out;
        if (C2)
            *reinterpret_cast<float4*>(&C2[(long long)m * ldc2 + n]) = out;
    }
}

// ---------------------------------------------------------------------------
// Split fp32 -> scaled fp16 pair:  x ~= x1 + x2/1024  (error ~2^-22 |x|).
// ---------------------------------------------------------------------------
__global__ __launch_bounds__(256) void split_f16(
    const float* __restrict__ src, _Float16* __restrict__ d1,
    _Float16* __restrict__ d2, int n4)
{
    int i = blockIdx.x * 256 + threadIdx.x;
    if (i >= n4) return;
    float4 v = reinterpret_cast<const float4*>(src)[i];
    float vv[4] = {v.x, v.y, v.z, v.w};
    f16x4 o1, o2;
#pragma unroll
    for (int j = 0; j < 4; ++j) {
        _Float16 hh = (_Float16)vv[j];
        o1[j] = hh;
        o2[j] = (_Float16)((vv[j] - (float)hh) * SPLIT_S);
    }
    *reinterpret_cast<f16x4*>(d1 + 4 * i) = o1;
    *reinterpret_cast<f16x4*>(d2 + 4 * i) = o2;
}

// ---------------------------------------------------------------------------
// Fused MFMA LSTM step.  Tile 64 batch x 32 h (=128 gate-major cols),
// 256 thr = 4 waves (2m x 2n), 48 KB LDS -> grid 512 blocks = 2 blocks/CU:
// while one block drains its stage barrier the other issues MFMAs
// (cross-block latency hiding; in-block prefetch regressed in R4).
// ---------------------------------------------------------------------------
__global__ __launch_bounds__(256) void lstm_step_mfma(
    const _Float16* __restrict__ hx1, const _Float16* __restrict__ hx2,
    float* __restrict__ cx,
    const _Float16* __restrict__ W1, const _Float16* __restrict__ W2, // [4H][H]
    const float* __restrict__ P,      // [D][4H] gather table (fp32)
    const int* __restrict__ m_prev,   // [B] or nullptr
    const float* __restrict__ bih, const float* __restrict__ bhh,
    _Float16* __restrict__ ho1, _Float16* __restrict__ ho2,
    float* __restrict__ hof)          // fp32 hx out (nullptr to skip)
{
    __shared__ __align__(16) _Float16 As1[64 * 64];
    __shared__ __align__(16) _Float16 As2[64 * 64];
    __shared__ __align__(16) _Float16 Ws1[128 * 64];
    __shared__ __align__(16) _Float16 Ws2[128 * 64];
    __shared__ int ms[64];

    const int tid = threadIdx.x;
    const int m0 = blockIdx.y * 64, h0 = blockIdx.x * 32;
    const int ln = tid & 63, wid = tid >> 6;
    const int wm = wid >> 1, wn = wid & 1;

    if (m_prev != nullptr && tid < 64) ms[tid] = m_prev[m0 + tid];

    f32x4 accM[2][4] = {};
    f32x4 accC[2][4] = {};

    for (int k0 = 0; k0 < H_; k0 += 64) {
        int jsw = ((ln & 7) ^ (ln >> 3)) << 3;
#pragma unroll
        for (int s = 0; s < 2; ++s) {           // A: 8 segments over 4 waves
            int seg = wid + s * 4;
            int r   = seg * 8 + (ln >> 3);
            size_t ga = (size_t)(m0 + r) * H_ + k0 + jsw;
            gload16(hx1 + ga, &As1[seg * 512]);
            gload16(hx2 + ga, &As2[seg * 512]);
        }
#pragma unroll
        for (int s = 0; s < 4; ++s) {           // W: 16 segments over 4 waves
            int seg = wid + s * 4;
            int r   = seg * 8 + (ln >> 3);
            int wrow = ((r >> 4) & 3) * H_ + h0 + ((r >> 6) << 4) + (r & 15);
            size_t gw = (size_t)wrow * H_ + k0 + jsw;
            gload16(W1 + gw, &Ws1[seg * 512]);
            gload16(W2 + gw, &Ws2[seg * 512]);
        }
        __syncthreads();
        const int ac = (ln >> 4) << 3;
        const int arow = wm * 32 + (ln & 15);
        const int brow = wn * 64 + (ln & 15);
#pragma unroll
        for (int kc = 0; kc < 2; ++kc) {
            int ko = kc * 32 + ac;
            f16x8 b1[4], b2[4];
#pragma unroll
            for (int fn = 0; fn < 4; ++fn) {
                b1[fn] = lds_frag(Ws1, brow + fn * 16, ko);
                b2[fn] = lds_frag(Ws2, brow + fn * 16, ko);
            }
#pragma unroll
            for (int fm = 0; fm < 2; ++fm) {
                f16x8 a1 = lds_frag(As1, arow + fm * 16, ko);
                f16x8 a2 = lds_frag(As2, arow + fm * 16, ko);
#pragma unroll
                for (int fn = 0; fn < 4; ++fn) {
                    accM[fm][fn] = __builtin_amdgcn_mfma_f32_16x16x32_f16(
                        a1, b1[fn], accM[fm][fn], 0, 0, 0);
                    accC[fm][fn] = __builtin_amdgcn_mfma_f32_16x16x32_f16(
                        a1, b2[fn], accC[fm][fn], 0, 0, 0);
                    accC[fm][fn] = __builtin_amdgcn_mfma_f32_16x16x32_f16(
                        a2, b1[fn], accC[fm][fn], 0, 0, 0);
                }
            }
        }
        __syncthreads();
    }

    // ---- epilogue: each lane owns (h, all 4 gates) for 8 batch rows ----
    const int hl = ln & 15;
    const int h  = h0 + wn * 16 + hl;
    const int rb = m0 + wm * 32 + ((ln >> 4) << 2);
    float bs0 = bih[0 * H_ + h] + bhh[0 * H_ + h];
    float bs1 = bih[1 * H_ + h] + bhh[1 * H_ + h];
    float bs2 = bih[2 * H_ + h] + bhh[2 * H_ + h];
    float bs3 = bih[3 * H_ + h] + bhh[3 * H_ + h];
#pragma unroll
    for (int fm = 0; fm < 2; ++fm) {
#pragma unroll
        for (int rg = 0; rg < 4; ++rg) {
            int b = rb + fm * 16 + rg;
            float g0 = accM[fm][0][rg] + SPLIT_RS * accC[fm][0][rg] + bs0;
            float g1 = accM[fm][1][rg] + SPLIT_RS * accC[fm][1][rg] + bs1;
            float g2 = accM[fm][2][rg] + SPLIT_RS * accC[fm][2][rg] + bs2;
            float g3 = accM[fm][3][rg] + SPLIT_RS * accC[fm][3][rg] + bs3;
            if (m_prev != nullptr) {
                const float* Pr = P + (size_t)ms[b - m0] * H4_;
                g0 += Pr[0 * H_ + h]; g1 += Pr[1 * H_ + h];
                g2 += Pr[2 * H_ + h]; g3 += Pr[3 * H_ + h];
            }
            float ig = 1.f / (1.f + expf(-g0));
            float fg = 1.f / (1.f + expf(-g1));
            float gg = tanhf(g2);
            float og = 1.f / (1.f + expf(-g3));
            size_t off = (size_t)b * H_ + h;
            float cnew = fg * cx[off] + ig * gg;
            cx[off] = cnew;
            float hv = og * tanhf(cnew);
            _Float16 hh1 = (_Float16)hv;
            ho1[off] = hh1;
            ho2[off] = (_Float16)((hv - (float)hh1) * SPLIT_S);
            if (hof != nullptr) hof[off] = hv;
        }
    }
}

// ---------------------------------------------------------------------------
// MFMA split-fp16 pre-GEMM with fused argmax partials.  Tile 64x64,
// 256 thr = 4 waves (2m x 2n), 32 KB LDS -> grid 512 = 2 blocks/CU.
// Partials go to pbest/pidx[b][16]; argmax_fin reduces them.
// ---------------------------------------------------------------------------
__global__ __launch_bounds__(256) void gemm_pre_fused(
    const _Float16* __restrict__ A1, const _Float16* __restrict__ A2, // [B][H]
    const _Float16* __restrict__ W1, const _Float16* __restrict__ W2, // [D][H]
    const float* __restrict__ bias,
    float* __restrict__ C2, int ldc2,   // logits slice (offset by l*D)
    const float* __restrict__ gum,      // gumbel + l*B*D  -> [B][D]
    float* __restrict__ pbest, int* __restrict__ pidx)  // [B][16]
{
    __shared__ __align__(16) _Float16 As1[64 * 64];
    __shared__ __align__(16) _Float16 As2[64 * 64];
    __shared__ __align__(16) _Float16 Ws1[64 * 64];
    __shared__ __align__(16) _Float16 Ws2[64 * 64];
    __shared__ float cb[2][64];
    __shared__ int   ci[2][64];

    const int tid = threadIdx.x;
    const int m0 = blockIdx.y * 64, n0 = blockIdx.x * 64;
    const int ln = tid & 63, wid = tid >> 6;
    const int wm = wid >> 1, wn = wid & 1;

    f32x4 accM[2][2] = {};
    f32x4 accC[2][2] = {};

    for (int k0 = 0; k0 < H_; k0 += 64) {
        int jsw = ((ln & 7) ^ (ln >> 3)) << 3;
#pragma unroll
        for (int s = 0; s < 2; ++s) {           // A: 8 segments over 4 waves
            int seg = wid + s * 4;
            int r   = seg * 8 + (ln >> 3);
            size_t ga = (size_t)(m0 + r) * H_ + k0 + jsw;
            gload16(A1 + ga, &As1[seg * 512]);
            gload16(A2 + ga, &As2[seg * 512]);
        }
#pragma unroll
        for (int s = 0; s < 2; ++s) {           // W: 8 segments over 4 waves
            int seg = wid + s * 4;
            int r   = seg * 8 + (ln >> 3);
            size_t gw = (size_t)(n0 + r) * H_ + k0 + jsw;
            gload16(W1 + gw, &Ws1[seg * 512]);
            gload16(W2 + gw, &Ws2[seg * 512]);
        }
        __syncthreads();
        const int ac = (ln >> 4) << 3;
        const int arow = wm * 32 + (ln & 15);
        const int brow = wn * 32 + (ln & 15);
#pragma unroll
        for (int kc = 0; kc < 2; ++kc) {
            int ko = kc * 32 + ac;
            f16x8 b1[2], b2[2];
#pragma unroll
            for (int fn = 0; fn < 2; ++fn) {
                b1[fn] = lds_frag(Ws1, brow + fn * 16, ko);
                b2[fn] = lds_frag(Ws2, brow + fn * 16, ko);
            }
#pragma unroll
            for (int fm = 0; fm < 2; ++fm) {
                f16x8 a1 = lds_frag(As1, arow + fm * 16, ko);
                f16x8 a2 = lds_frag(As2, arow + fm * 16, ko);
#pragma unroll
                for (int fn = 0; fn < 2; ++fn) {
                    accM[fm][fn] = __builtin_amdgcn_mfma_f32_16x16x32_f16(
                        a1, b1[fn], accM[fm][fn], 0, 0, 0);
                    accC[fm][fn] = __builtin_amdgcn_mfma_f32_16x16x32_f16(
                        a1, b2[fn], accC[fm][fn], 0, 0, 0);
                    accC[fm][fn] = __builtin_amdgcn_mfma_f32_16x16x32_f16(
                        a2, b1[fn], accC[fm][fn], 0, 0, 0);
                }
            }
        }
        __syncthreads();
    }

    // ---- epilogue: write logits; fold gumbel; per-block argmax partial ----
    const int hl = ln & 15;
    const int g4 = ln >> 4;
    const int rb = m0 + wm * 32 + (g4 << 2);
    float vbest[2][4]; int vidx[2][4];
#pragma unroll
    for (int fm = 0; fm < 2; ++fm)
#pragma unroll
        for (int rg = 0; rg < 4; ++rg) { vbest[fm][rg] = -INFINITY; vidx[fm][rg] = 0; }

#pragma unroll
    for (int fn = 0; fn < 2; ++fn) {
        int d = n0 + wn * 32 + fn * 16 + hl;
        float bv = bias[d];
#pragma unroll
        for (int fm = 0; fm < 2; ++fm)
#pragma unroll
            for (int rg = 0; rg < 4; ++rg) {
                int b = rb + fm * 16 + rg;
                float v = accM[fm][fn][rg] + SPLIT_RS * accC[fm][fn][rg] + bv;
                C2[(size_t)b * ldc2 + d] = v;
                float t = v + gum[(size_t)b * D_ + d];
                if (t > vbest[fm][rg]) { vbest[fm][rg] = t; vidx[fm][rg] = d; }
            }
    }

    // butterfly over the 16 hl lanes (d ascending with fn; ties keep low d)
#pragma unroll
    for (int off = 1; off < 16; off <<= 1) {
#pragma unroll
        for (int fm = 0; fm < 2; ++fm)
#pragma unroll
            for (int rg = 0; rg < 4; ++rg) {
                float ov = __shfl_xor(vbest[fm][rg], off);
                int   oi = __shfl_xor(vidx[fm][rg], off);
                if (ov > vbest[fm][rg] ||
                    (ov == vbest[fm][rg] && oi < vidx[fm][rg])) {
                    vbest[fm][rg] = ov; vidx[fm][rg] = oi;
                }
            }
    }
    if (hl == 0) {
#pragma unroll
        for (int fm = 0; fm < 2; ++fm)
#pragma unroll
            for (int rg = 0; rg < 4; ++rg) {
                int rl = wm * 32 + fm * 16 + (g4 << 2) + rg;
                cb[wn][rl] = vbest[fm][rg];
                ci[wn][rl] = vidx[fm][rg];
            }
    }
    __syncthreads();
    if (tid < 64) {
        float b0 = cb[0][tid]; int i0 = ci[0][tid];
        float b1v = cb[1][tid]; int i1 = ci[1][tid];
        if (b1v > b0 || (b1v == b0 && i1 < i0)) { b0 = b1v; i0 = i1; }
        pbest[(size_t)(m0 + tid) * 16 + blockIdx.x] = b0;
        pidx [(size_t)(m0 + tid) * 16 + blockIdx.x] = i0;
    }
}

// final reduce of the 16 per-block partials; writes messages/onehot/m_out
__global__ __launch_bounds__(256) void argmax_fin(
    const float* __restrict__ pbest, const int* __restrict__ pidx,
    float* __restrict__ onehot, float* __restrict__ messages,
    int* __restrict__ m_out, int l)
{
    int b = blockIdx.x * 256 + threadIdx.x;
    float best = -INFINITY; int bi = 0;
#pragma unroll
    for (int j = 0; j < 16; ++j) {
        float v = pbest[(size_t)b * 16 + j];
        int   i = pidx [(size_t)b * 16 + j];
        if (v > best || (v == best && i < bi)) { best = v; bi = i; }
    }
    m_out[b] = bi;
    messages[(size_t)b * L_ + l] = (float)bi;
    onehot[((size_t)b * L_ + l) * D_ + bi] = 1.0f;
}

// t2h_emb[d, h] = t2h_W[h, d] + t2h_b[h]
__global__ __launch_bounds__(256) void build_emb(
    const float* __restrict__ t2h_W, const float* __restrict__ t2h_b,
    float* __restrict__ emb)
{
    int idx = blockIdx.x * 256 + threadIdx.x;
    int d = idx >> 9, h = idx & (H_ - 1);
    emb[idx] = t2h_W[(long long)h * D_ + d] + t2h_b[h];
}

// ---------------------------------------------------------------------------
extern "C" void kernel_launch(void* const* d_in, const int* in_sizes, int n_in,
                              void* d_out, int out_size, void* d_ws, size_t ws_size,
                              hipStream_t stream)
{
    (void)in_sizes; (void)n_in; (void)out_size; (void)ws_size;
    const float* x       = (const float*)d_in[0];
    const float* gumbel  = (const float*)d_in[1];
    const float* in_W    = (const float*)d_in[2];
    const float* in_b    = (const float*)d_in[3];
    const float* out_W   = (const float*)d_in[4];
    const float* out_b   = (const float*)d_in[5];
    const float* enc_Wih = (const float*)d_in[6];
    const float* enc_Whh = (const float*)d_in[7];
    const float* enc_bih = (const float*)d_in[8];
    const float* enc_bhh = (const float*)d_in[9];
    const float* dec_Wih = (const float*)d_in[10];
    const float* dec_Whh = (const float*)d_in[11];
    const float* dec_bih = (const float*)d_in[12];
    const float* dec_bhh = (const float*)d_in[13];
    const float* h2t_W   = (const float*)d_in[14];
    const float* h2t_b   = (const float*)d_in[15];
    const float* t2h_W   = (const float*)d_in[16];
    const float* t2h_b   = (const float*)d_in[17];

    float* out      = (float*)d_out;
    float* recon    = out;                                  // [B,O]
    float* onehot   = out + (size_t)B_ * O_;                // [B,L,D]
    float* logits   = onehot + (size_t)B_ * L_ * D_;        // [B,L,D]
    float* messages = logits + (size_t)B_ * L_ * D_;        // [B,L]

    float* ws    = (float*)d_ws;
    float* cx    = ws;                                      // [B,H]
    float* emb   = cx + (size_t)B_ * H_;                    // [D,H]
    float* P_enc = emb + (size_t)D_ * H_;                   // [D,4H]
    float* P_dec = P_enc + (size_t)D_ * H4_;                // [D,4H]
    float* hxf   = P_dec + (size_t)D_ * H4_;                // [B,H]
    float* pbest = hxf + (size_t)B_ * H_;                   // [B,16]
    int*   pidx  = (int*)(pbest + (size_t)B_ * 16);         // [B,16]
    int*   m_all = pidx + (size_t)B_ * 16;                  // [L,B]
    _Float16* fb   = (_Float16*)(m_all + (size_t)L_ * B_);
    _Float16* hxA1 = fb;  fb += (size_t)B_ * H_;
    _Float16* hxA2 = fb;  fb += (size_t)B_ * H_;
    _Float16* hxB1 = fb;  fb += (size_t)B_ * H_;
    _Float16* hxB2 = fb;  fb += (size_t)B_ * H_;
    _Float16* encW1 = fb; fb += (size_t)H4_ * H_;
    _Float16* encW2 = fb; fb += (size_t)H4_ * H_;
    _Float16* decW1 = fb; fb += (size_t)H4_ * H_;
    _Float16* decW2 = fb; fb += (size_t)H4_ * H_;
    _Float16* h2t1  = fb; fb += (size_t)D_ * H_;
    _Float16* h2t2  = fb;

    const dim3 blk256(256);

    (void)hipMemsetAsync(hxA1, 0, (size_t)B_ * H_ * 4, stream);
    (void)hipMemsetAsync(onehot, 0, (size_t)B_ * L_ * D_ * sizeof(float), stream);

    // weight splits (one-time)
    split_f16<<<dim3((H4_ * H_ / 4) / 256), blk256, 0, stream>>>(
        enc_Whh, encW1, encW2, H4_ * H_ / 4);
    split_f16<<<dim3((H4_ * H_ / 4) / 256), blk256, 0, stream>>>(
        dec_Whh, decW1, decW2, H4_ * H_ / 4);
    split_f16<<<dim3((D_ * H_ / 4) / 256), blk256, 0, stream>>>(
        h2t_W, h2t1, h2t2, D_ * H_ / 4);

    // cx0 (encoder initial cell state) = x @ in_W^T + in_b  (fp32)
    gemm_atb<<<dim3(H_ / 64, B_ / 64), blk256, 0, stream>>>(
        x, in_W, in_b, cx, H_, nullptr, 0, B_, H_, I_);

    // one-hot decode table and the two precomputed gather tables (fp32)
    build_emb<<<dim3((D_ * H_) / 256), blk256, 0, stream>>>(t2h_W, t2h_b, emb);
    gemm_atb<<<dim3(H4_ / 64, D_ / 64), blk256, 0, stream>>>(
        emb, enc_Wih, nullptr, P_enc, H4_, nullptr, 0, D_, H4_, H_);
    gemm_atb<<<dim3(H4_ / 64, D_ / 64), blk256, 0, stream>>>(
        emb, dec_Wih, nullptr, P_dec, H4_, nullptr, 0, D_, H4_, H_);

    // ---------------- encoder ----------------
    _Float16 *c1 = hxA1, *c2 = hxA2, *n1 = hxB1, *n2 = hxB2;
    for (int l = 0; l < L_; ++l) {
        lstm_step_mfma<<<dim3(H_ / 32, B_ / 64), blk256, 0, stream>>>(
            c1, c2, cx, encW1, encW2, P_enc,
            (l == 0) ? nullptr : (m_all + (size_t)(l - 1) * B_),
            enc_bih, enc_bhh, n1, n2, nullptr);
        { _Float16* t = c1; c1 = n1; n1 = t; t = c2; c2 = n2; n2 = t; }
        gemm_pre_fused<<<dim3(D_ / 64, B_ / 64), blk256, 0, stream>>>(
            c1, c2, h2t1, h2t2, h2t_b,
            logits + (size_t)l * D_, L_ * D_,
            gumbel + (size_t)l * B_ * D_, pbest, pidx);
        argmax_fin<<<dim3(B_ / 256), blk256, 0, stream>>>(
            pbest, pidx, onehot, messages, m_all + (size_t)l * B_, l);
    }

    // ---------------- decoder ----------------
    (void)hipMemsetAsync(c1, 0, (size_t)B_ * H_ * 2, stream);
    (void)hipMemsetAsync(c2, 0, (size_t)B_ * H_ * 2, stream);
    (void)hipMemsetAsync(cx, 0, (size_t)B_ * H_ * sizeof(float), stream);
    for (int l = 0; l < L_; ++l) {
        lstm_step_mfma<<<dim3(H_ / 32, B_ / 64), blk256, 0, stream>>>(
            c1, c2, cx, decW1, decW2, P_dec, m_all + (size_t)l * B_,
            dec_bih, dec_bhh, n1, n2, (l == L_ - 1) ? hxf : nullptr);
        { _Float16* t = c1; c1 = n1; n1 = t; t = c2; c2 = n2; n2 = t; }
    }

    // recon = hx_final @ out_W^T + out_b  (fp32)
    gemm_atb<<<dim3(O_ / 64, B_ / 64), blk256, 0, stream>>>(
        hxf, out_W, out_b, recon, O_, nullptr, 0, B_, O_, H_);
}

// Round 6
// 2847.928 us; speedup vs baseline: 1.2484x; 1.0088x over previous
//
#include <hip/hip_runtime.h>
#include <math.h>

#define B_  2048
#define I_  512
#define H_  512
#define L_  32
#define D_  1024
#define O_  512
#define H4_ 2048
#define KC  32

typedef _Float16 f16x8 __attribute__((ext_vector_type(8)));
typedef _Float16 f16x4 __attribute__((ext_vector_type(4)));
typedef float    f32x4 __attribute__((ext_vector_type(4)));

#define SPLIT_S  1024.0f
#define SPLIT_RS 0.0009765625f   /* 1/1024 */

// async global->LDS, 16B per lane; LDS dest = wave-uniform base + lane*16
__device__ __forceinline__ void gload16(const _Float16* g, _Float16* l) {
    __builtin_amdgcn_global_load_lds(
        (const __attribute__((address_space(1))) void*)g,
        (__attribute__((address_space(3))) void*)l, 16, 0, 0);
}

// swizzled fragment read: LDS chunk c holds global chunk c^(row&7)
__device__ __forceinline__ f16x8 lds_frag(const _Float16* base, int row, int ko) {
    int off = row * 64 + ((((ko >> 3) ^ (row & 7))) << 3);
    return *(const f16x8*)(base + off);
}

// ---------------------------------------------------------------------------
// Generic fp32 GEMM (kept for one-time GEMMs: cx0, recon).
// ---------------------------------------------------------------------------
__global__ __launch_bounds__(256) void gemm_atb(
    const float* __restrict__ A, const float* __restrict__ W,
    const float* __restrict__ bias, float* __restrict__ C, int ldc,
    float* __restrict__ C2, int ldc2,
    int M, int N, int K)
{
    __shared__ __align__(16) float As[KC][68];
    __shared__ __align__(16) float Ws[KC][68];
    const int tx = threadIdx.x & 15, ty = threadIdx.x >> 4;
    const int m0 = blockIdx.y * 64, n0 = blockIdx.x * 64;
    float acc[4][4] = {};

    for (int k0 = 0; k0 < K; k0 += KC) {
#pragma unroll
        for (int p = 0; p < 2; ++p) {
            int q = threadIdx.x + 256 * p;
            int r = q >> 3, c = q & 7;
            float4 va = *reinterpret_cast<const float4*>(
                &A[(long long)(m0 + r) * K + k0 + c * 4]);
            As[c * 4 + 0][r] = va.x; As[c * 4 + 1][r] = va.y;
            As[c * 4 + 2][r] = va.z; As[c * 4 + 3][r] = va.w;
            float4 vw = *reinterpret_cast<const float4*>(
                &W[(long long)(n0 + r) * K + k0 + c * 4]);
            Ws[c * 4 + 0][r] = vw.x; Ws[c * 4 + 1][r] = vw.y;
            Ws[c * 4 + 2][r] = vw.z; Ws[c * 4 + 3][r] = vw.w;
        }
        __syncthreads();
#pragma unroll
        for (int kk = 0; kk < KC; ++kk) {
            float4 a = *reinterpret_cast<const float4*>(&As[kk][ty * 4]);
            float4 w = *reinterpret_cast<const float4*>(&Ws[kk][tx * 4]);
            float av[4] = {a.x, a.y, a.z, a.w};
            float wv[4] = {w.x, w.y, w.z, w.w};
#pragma unroll
            for (int i = 0; i < 4; ++i)
#pragma unroll
                for (int j = 0; j < 4; ++j)
                    acc[i][j] = fmaf(av[i], wv[j], acc[i][j]);
        }
        __syncthreads();
    }

#pragma unroll
    for (int i = 0; i < 4; ++i) {
        int m = m0 + ty * 4 + i;
        int n = n0 + tx * 4;
        float4 out;
        out.x = acc[i][0]; out.y = acc[i][1]; out.z = acc[i][2]; out.w = acc[i][3];
        if (bias) {
            out.x += bias[n + 0]; out.y += bias[n + 1];
            out.z += bias[n + 2]; out.w += bias[n + 3];
        }
        *reinterpret_cast<float4*>(&C[(long long)m * ldc + n]) = out;
        if (C2)
            *reinterpret_cast<float4*>(&C2[(long long)m * ldc2 + n]) = out;
    }
}

// ---------------------------------------------------------------------------
// Split fp32 -> scaled fp16 pair:  x ~= x1 + x2/1024  (error ~2^-22 |x|).
// ---------------------------------------------------------------------------
__global__ __launch_bounds__(256) void split_f16(
    const float* __restrict__ src, _Float16* __restrict__ d1,
    _Float16* __restrict__ d2, int n4)
{
    int i = blockIdx.x * 256 + threadIdx.x;
    if (i >= n4) return;
    float4 v = reinterpret_cast<const float4*>(src)[i];
    float vv[4] = {v.x, v.y, v.z, v.w};
    f16x4 o1, o2;
#pragma unroll
    for (int j = 0; j < 4; ++j) {
        _Float16 hh = (_Float16)vv[j];
        o1[j] = hh;
        o2[j] = (_Float16)((vv[j] - (float)hh) * SPLIT_S);
    }
    *reinterpret_cast<f16x4*>(d1 + 4 * i) = o1;
    *reinterpret_cast<f16x4*>(d2 + 4 * i) = o2;
}

// ---------------------------------------------------------------------------
// Generic split-f16 MFMA GEMM: C[M,N] = A[M,K] @ W[N,K]^T (fp32 out).
// Tile 64x64, 4 waves, 32 KB LDS.  Used for the P gather tables.
// ---------------------------------------------------------------------------
__global__ __launch_bounds__(256) void gemm_mfma_atb(
    const _Float16* __restrict__ A1, const _Float16* __restrict__ A2, // [M][K]
    const _Float16* __restrict__ W1, const _Float16* __restrict__ W2, // [N][K]
    float* __restrict__ C, int N, int K)
{
    __shared__ __align__(16) _Float16 As1[64 * 64];
    __shared__ __align__(16) _Float16 As2[64 * 64];
    __shared__ __align__(16) _Float16 Ws1[64 * 64];
    __shared__ __align__(16) _Float16 Ws2[64 * 64];

    const int tid = threadIdx.x;
    const int m0 = blockIdx.y * 64, n0 = blockIdx.x * 64;
    const int ln = tid & 63, wid = tid >> 6;
    const int wm = wid >> 1, wn = wid & 1;

    f32x4 accM[2][2] = {};
    f32x4 accC[2][2] = {};

    for (int k0 = 0; k0 < K; k0 += 64) {
        int jsw = ((ln & 7) ^ (ln >> 3)) << 3;
#pragma unroll
        for (int s = 0; s < 2; ++s) {
            int seg = wid + s * 4;
            int r   = seg * 8 + (ln >> 3);
            size_t ga = (size_t)(m0 + r) * K + k0 + jsw;
            gload16(A1 + ga, &As1[seg * 512]);
            gload16(A2 + ga, &As2[seg * 512]);
            size_t gw = (size_t)(n0 + r) * K + k0 + jsw;
            gload16(W1 + gw, &Ws1[seg * 512]);
            gload16(W2 + gw, &Ws2[seg * 512]);
        }
        __syncthreads();
        const int ac = (ln >> 4) << 3;
        const int arow = wm * 32 + (ln & 15);
        const int brow = wn * 32 + (ln & 15);
#pragma unroll
        for (int kc = 0; kc < 2; ++kc) {
            int ko = kc * 32 + ac;
            f16x8 b1[2], b2[2];
#pragma unroll
            for (int fn = 0; fn < 2; ++fn) {
                b1[fn] = lds_frag(Ws1, brow + fn * 16, ko);
                b2[fn] = lds_frag(Ws2, brow + fn * 16, ko);
            }
#pragma unroll
            for (int fm = 0; fm < 2; ++fm) {
                f16x8 a1 = lds_frag(As1, arow + fm * 16, ko);
                f16x8 a2 = lds_frag(As2, arow + fm * 16, ko);
#pragma unroll
                for (int fn = 0; fn < 2; ++fn) {
                    accM[fm][fn] = __builtin_amdgcn_mfma_f32_16x16x32_f16(
                        a1, b1[fn], accM[fm][fn], 0, 0, 0);
                    accC[fm][fn] = __builtin_amdgcn_mfma_f32_16x16x32_f16(
                        a1, b2[fn], accC[fm][fn], 0, 0, 0);
                    accC[fm][fn] = __builtin_amdgcn_mfma_f32_16x16x32_f16(
                        a2, b1[fn], accC[fm][fn], 0, 0, 0);
                }
            }
        }
        __syncthreads();
    }

    const int hl = ln & 15;
    const int rb = m0 + wm * 32 + ((ln >> 4) << 2);
#pragma unroll
    for (int fn = 0; fn < 2; ++fn) {
        int d = n0 + wn * 32 + fn * 16 + hl;
#pragma unroll
        for (int fm = 0; fm < 2; ++fm)
#pragma unroll
            for (int rg = 0; rg < 4; ++rg) {
                int b = rb + fm * 16 + rg;
                C[(size_t)b * N + d] =
                    accM[fm][fn][rg] + SPLIT_RS * accC[fm][fn][rg];
            }
    }
}

// ---------------------------------------------------------------------------
// FUSED enc+dec LSTM step.  Tile 64 batch x 32 h, 256 thr = 4 waves,
// 48 KB LDS -> 3 blocks/CU; grid z selects role (0 = enc step l,
// 1 = dec step l-1) so both LSTMs co-run and hide each other's stage drain.
// Per-block inline reduce of the 16 argmax partials replaces argmax_fin;
// the z=0,x=0 blocks write messages/onehot for step lmsg.
// ---------------------------------------------------------------------------
__global__ __launch_bounds__(256) void lstm_fused(
    const _Float16* __restrict__ ehx1, const _Float16* __restrict__ ehx2,
    float* __restrict__ ecx,
    const _Float16* __restrict__ eW1, const _Float16* __restrict__ eW2,
    const float* __restrict__ Pe,
    const float* __restrict__ ebih, const float* __restrict__ ebhh,
    _Float16* __restrict__ eho1, _Float16* __restrict__ eho2,
    const _Float16* __restrict__ dhx1, const _Float16* __restrict__ dhx2,
    float* __restrict__ dcx,
    const _Float16* __restrict__ dW1, const _Float16* __restrict__ dW2,
    const float* __restrict__ Pd,
    const float* __restrict__ dbih, const float* __restrict__ dbhh,
    _Float16* __restrict__ dho1, _Float16* __restrict__ dho2,
    float* __restrict__ hof,          // fp32 hx out (dec final only)
    const float* __restrict__ pbest, const int* __restrict__ pidx, // [B][16]
    int have_gather,
    float* __restrict__ onehot, float* __restrict__ messages, int lmsg,
    int encdec)                       // 1=enc only, 2=dec only, 3=both (z)
{
    __shared__ __align__(16) _Float16 As1[64 * 64];
    __shared__ __align__(16) _Float16 As2[64 * 64];
    __shared__ __align__(16) _Float16 Ws1[128 * 64];
    __shared__ __align__(16) _Float16 Ws2[128 * 64];
    __shared__ int ms[64];

    const int tid = threadIdx.x;
    const int m0 = blockIdx.y * 64, h0 = blockIdx.x * 32;
    const int ln = tid & 63, wid = tid >> 6;
    const int wm = wid >> 1, wn = wid & 1;
    const int role = (encdec == 3) ? (int)blockIdx.z : ((encdec & 1) ? 0 : 1);

    const _Float16* hx1 = role ? dhx1 : ehx1;
    const _Float16* hx2 = role ? dhx2 : ehx2;
    float*          cx  = role ? dcx  : ecx;
    const _Float16* W1  = role ? dW1  : eW1;
    const _Float16* W2  = role ? dW2  : eW2;
    const float*    P   = role ? Pd   : Pe;
    const float*    bih = role ? dbih : ebih;
    const float*    bhh = role ? dbhh : ebhh;
    _Float16*       ho1 = role ? dho1 : eho1;
    _Float16*       ho2 = role ? dho2 : eho2;

    // inline argmax over the 16 per-block partials of the previous pre step
    if (have_gather && tid < 64) {
        int b = m0 + tid;
        const float* pb = pbest + (size_t)b * 16;
        const int*   pi = pidx  + (size_t)b * 16;
        float best = -INFINITY; int bi = 0;
#pragma unroll
        for (int j = 0; j < 16; ++j) {
            float v = pb[j]; int i = pi[j];
            if (v > best || (v == best && i < bi)) { best = v; bi = i; }
        }
        ms[tid] = bi;
        if (lmsg >= 0 && blockIdx.z == 0 && blockIdx.x == 0) {
            messages[(size_t)b * L_ + lmsg] = (float)bi;
            onehot[((size_t)b * L_ + lmsg) * D_ + bi] = 1.0f;
        }
    }

    f32x4 accM[2][4] = {};
    f32x4 accC[2][4] = {};

    for (int k0 = 0; k0 < H_; k0 += 64) {
        int jsw = ((ln & 7) ^ (ln >> 3)) << 3;
#pragma unroll
        for (int s = 0; s < 2; ++s) {           // A: 8 segments over 4 waves
            int seg = wid + s * 4;
            int r   = seg * 8 + (ln >> 3);
            size_t ga = (size_t)(m0 + r) * H_ + k0 + jsw;
            gload16(hx1 + ga, &As1[seg * 512]);
            gload16(hx2 + ga, &As2[seg * 512]);
        }
#pragma unroll
        for (int s = 0; s < 4; ++s) {           // W: 16 segments over 4 waves
            int seg = wid + s * 4;
            int r   = seg * 8 + (ln >> 3);
            int wrow = ((r >> 4) & 3) * H_ + h0 + ((r >> 6) << 4) + (r & 15);
            size_t gw = (size_t)wrow * H_ + k0 + jsw;
            gload16(W1 + gw, &Ws1[seg * 512]);
            gload16(W2 + gw, &Ws2[seg * 512]);
        }
        __syncthreads();
        const int ac = (ln >> 4) << 3;
        const int arow = wm * 32 + (ln & 15);
        const int brow = wn * 64 + (ln & 15);
#pragma unroll
        for (int kc = 0; kc < 2; ++kc) {
            int ko = kc * 32 + ac;
            f16x8 b1[4], b2[4];
#pragma unroll
            for (int fn = 0; fn < 4; ++fn) {
                b1[fn] = lds_frag(Ws1, brow + fn * 16, ko);
                b2[fn] = lds_frag(Ws2, brow + fn * 16, ko);
            }
#pragma unroll
            for (int fm = 0; fm < 2; ++fm) {
                f16x8 a1 = lds_frag(As1, arow + fm * 16, ko);
                f16x8 a2 = lds_frag(As2, arow + fm * 16, ko);
#pragma unroll
                for (int fn = 0; fn < 4; ++fn) {
                    accM[fm][fn] = __builtin_amdgcn_mfma_f32_16x16x32_f16(
                        a1, b1[fn], accM[fm][fn], 0, 0, 0);
                    accC[fm][fn] = __builtin_amdgcn_mfma_f32_16x16x32_f16(
                        a1, b2[fn], accC[fm][fn], 0, 0, 0);
                    accC[fm][fn] = __builtin_amdgcn_mfma_f32_16x16x32_f16(
                        a2, b1[fn], accC[fm][fn], 0, 0, 0);
                }
            }
        }
        __syncthreads();
    }

    // ---- epilogue: each lane owns (h, all 4 gates) for 8 batch rows ----
    const int hl = ln & 15;
    const int h  = h0 + wn * 16 + hl;
    const int rb = m0 + wm * 32 + ((ln >> 4) << 2);
    float bs0 = bih[0 * H_ + h] + bhh[0 * H_ + h];
    float bs1 = bih[1 * H_ + h] + bhh[1 * H_ + h];
    float bs2 = bih[2 * H_ + h] + bhh[2 * H_ + h];
    float bs3 = bih[3 * H_ + h] + bhh[3 * H_ + h];
#pragma unroll
    for (int fm = 0; fm < 2; ++fm) {
#pragma unroll
        for (int rg = 0; rg < 4; ++rg) {
            int b = rb + fm * 16 + rg;
            float g0 = accM[fm][0][rg] + SPLIT_RS * accC[fm][0][rg] + bs0;
            float g1 = accM[fm][1][rg] + SPLIT_RS * accC[fm][1][rg] + bs1;
            float g2 = accM[fm][2][rg] + SPLIT_RS * accC[fm][2][rg] + bs2;
            float g3 = accM[fm][3][rg] + SPLIT_RS * accC[fm][3][rg] + bs3;
            if (have_gather) {
                const float* Pr = P + (size_t)ms[b - m0] * H4_;
                g0 += Pr[0 * H_ + h]; g1 += Pr[1 * H_ + h];
                g2 += Pr[2 * H_ + h]; g3 += Pr[3 * H_ + h];
            }
            float ig = 1.f / (1.f + expf(-g0));
            float fg = 1.f / (1.f + expf(-g1));
            float gg = tanhf(g2);
            float og = 1.f / (1.f + expf(-g3));
            size_t off = (size_t)b * H_ + h;
            float cnew = fg * cx[off] + ig * gg;
            cx[off] = cnew;
            float hv = og * tanhf(cnew);
            _Float16 hh1 = (_Float16)hv;
            ho1[off] = hh1;
            ho2[off] = (_Float16)((hv - (float)hh1) * SPLIT_S);
            if (role && hof != nullptr) hof[off] = hv;
        }
    }
}

// ---------------------------------------------------------------------------
// MFMA split-fp16 pre-GEMM with fused argmax partials.  Tile 64x64,
// 256 thr = 4 waves (2m x 2n), 32 KB LDS -> 2+ blocks/CU.
// Partials go to pbest/pidx[b][16]; consumed inline by the next lstm_fused.
// ---------------------------------------------------------------------------
__global__ __launch_bounds__(256) void gemm_pre_fused(
    const _Float16* __restrict__ A1, const _Float16* __restrict__ A2, // [B][H]
    const _Float16* __restrict__ W1, const _Float16* __restrict__ W2, // [D][H]
    const float* __restrict__ bias,
    float* __restrict__ C2, int ldc2,   // logits slice (offset by l*D)
    const float* __restrict__ gum,      // gumbel + l*B*D  -> [B][D]
    float* __restrict__ pbest, int* __restrict__ pidx)  // [B][16]
{
    __shared__ __align__(16) _Float16 As1[64 * 64];
    __shared__ __align__(16) _Float16 As2[64 * 64];
    __shared__ __align__(16) _Float16 Ws1[64 * 64];
    __shared__ __align__(16) _Float16 Ws2[64 * 64];
    __shared__ float cb[2][64];
    __shared__ int   ci[2][64];

    const int tid = threadIdx.x;
    const int m0 = blockIdx.y * 64, n0 = blockIdx.x * 64;
    const int ln = tid & 63, wid = tid >> 6;
    const int wm = wid >> 1, wn = wid & 1;

    f32x4 accM[2][2] = {};
    f32x4 accC[2][2] = {};

    for (int k0 = 0; k0 < H_; k0 += 64) {
        int jsw = ((ln & 7) ^ (ln >> 3)) << 3;
#pragma unroll
        for (int s = 0; s < 2; ++s) {
            int seg = wid + s * 4;
            int r   = seg * 8 + (ln >> 3);
            size_t ga = (size_t)(m0 + r) * H_ + k0 + jsw;
            gload16(A1 + ga, &As1[seg * 512]);
            gload16(A2 + ga, &As2[seg * 512]);
        }
#pragma unroll
        for (int s = 0; s < 2; ++s) {
            int seg = wid + s * 4;
            int r   = seg * 8 + (ln >> 3);
            size_t gw = (size_t)(n0 + r) * H_ + k0 + jsw;
            gload16(W1 + gw, &Ws1[seg * 512]);
            gload16(W2 + gw, &Ws2[seg * 512]);
        }
        __syncthreads();
        const int ac = (ln >> 4) << 3;
        const int arow = wm * 32 + (ln & 15);
        const int brow = wn * 32 + (ln & 15);
#pragma unroll
        for (int kc = 0; kc < 2; ++kc) {
            int ko = kc * 32 + ac;
            f16x8 b1[2], b2[2];
#pragma unroll
            for (int fn = 0; fn < 2; ++fn) {
                b1[fn] = lds_frag(Ws1, brow + fn * 16, ko);
                b2[fn] = lds_frag(Ws2, brow + fn * 16, ko);
            }
#pragma unroll
            for (int fm = 0; fm < 2; ++fm) {
                f16x8 a1 = lds_frag(As1, arow + fm * 16, ko);
                f16x8 a2 = lds_frag(As2, arow + fm * 16, ko);
#pragma unroll
                for (int fn = 0; fn < 2; ++fn) {
                    accM[fm][fn] = __builtin_amdgcn_mfma_f32_16x16x32_f16(
                        a1, b1[fn], accM[fm][fn], 0, 0, 0);
                    accC[fm][fn] = __builtin_amdgcn_mfma_f32_16x16x32_f16(
                        a1, b2[fn], accC[fm][fn], 0, 0, 0);
                    accC[fm][fn] = __builtin_amdgcn_mfma_f32_16x16x32_f16(
                        a2, b1[fn], accC[fm][fn], 0, 0, 0);
                }
            }
        }
        __syncthreads();
    }

    // ---- epilogue: write logits; fold gumbel; per-block argmax partial ----
    const int hl = ln & 15;
    const int g4 = ln >> 4;
    const int rb = m0 + wm * 32 + (g4 << 2);
    float vbest[2][4]; int vidx[2][4];
#pragma unroll
    for (int fm = 0; fm < 2; ++fm)
#pragma unroll
        for (int rg = 0; rg < 4; ++rg) { vbest[fm][rg] = -INFINITY; vidx[fm][rg] = 0; }

#pragma unroll
    for (int fn = 0; fn < 2; ++fn) {
        int d = n0 + wn * 32 + fn * 16 + hl;
        float bv = bias[d];
#pragma unroll
        for (int fm = 0; fm < 2; ++fm)
#pragma unroll
            for (int rg = 0; rg < 4; ++rg) {
                int b = rb + fm * 16 + rg;
                float v = accM[fm][fn][rg] + SPLIT_RS * accC[fm][fn][rg] + bv;
                C2[(size_t)b * ldc2 + d] = v;
                float t = v + gum[(size_t)b * D_ + d];
                if (t > vbest[fm][rg]) { vbest[fm][rg] = t; vidx[fm][rg] = d; }
            }
    }

#pragma unroll
    for (int off = 1; off < 16; off <<= 1) {
#pragma unroll
        for (int fm = 0; fm < 2; ++fm)
#pragma unroll
            for (int rg = 0; rg < 4; ++rg) {
                float ov = __shfl_xor(vbest[fm][rg], off);
                int   oi = __shfl_xor(vidx[fm][rg], off);
                if (ov > vbest[fm][rg] ||
                    (ov == vbest[fm][rg] && oi < vidx[fm][rg])) {
                    vbest[fm][rg] = ov; vidx[fm][rg] = oi;
                }
            }
    }
    if (hl == 0) {
#pragma unroll
        for (int fm = 0; fm < 2; ++fm)
#pragma unroll
            for (int rg = 0; rg < 4; ++rg) {
                int rl = wm * 32 + fm * 16 + (g4 << 2) + rg;
                cb[wn][rl] = vbest[fm][rg];
                ci[wn][rl] = vidx[fm][rg];
            }
    }
    __syncthreads();
    if (tid < 64) {
        float b0 = cb[0][tid]; int i0 = ci[0][tid];
        float b1v = cb[1][tid]; int i1 = ci[1][tid];
        if (b1v > b0 || (b1v == b0 && i1 < i0)) { b0 = b1v; i0 = i1; }
        pbest[(size_t)(m0 + tid) * 16 + blockIdx.x] = b0;
        pidx [(size_t)(m0 + tid) * 16 + blockIdx.x] = i0;
    }
}

// t2h_emb[d, h] = t2h_W[h, d] + t2h_b[h]
__global__ __launch_bounds__(256) void build_emb(
    const float* __restrict__ t2h_W, const float* __restrict__ t2h_b,
    float* __restrict__ emb)
{
    int idx = blockIdx.x * 256 + threadIdx.x;
    int d = idx >> 9, h = idx & (H_ - 1);
    emb[idx] = t2h_W[(long long)h * D_ + d] + t2h_b[h];
}

// ---------------------------------------------------------------------------
extern "C" void kernel_launch(void* const* d_in, const int* in_sizes, int n_in,
                              void* d_out, int out_size, void* d_ws, size_t ws_size,
                              hipStream_t stream)
{
    (void)in_sizes; (void)n_in; (void)out_size; (void)ws_size;
    const float* x       = (const float*)d_in[0];
    const float* gumbel  = (const float*)d_in[1];
    const float* in_W    = (const float*)d_in[2];
    const float* in_b    = (const float*)d_in[3];
    const float* out_W   = (const float*)d_in[4];
    const float* out_b   = (const float*)d_in[5];
    const float* enc_Wih = (const float*)d_in[6];
    const float* enc_Whh = (const float*)d_in[7];
    const float* enc_bih = (const float*)d_in[8];
    const float* enc_bhh = (const float*)d_in[9];
    const float* dec_Wih = (const float*)d_in[10];
    const float* dec_Whh = (const float*)d_in[11];
    const float* dec_bih = (const float*)d_in[12];
    const float* dec_bhh = (const float*)d_in[13];
    const float* h2t_W   = (const float*)d_in[14];
    const float* h2t_b   = (const float*)d_in[15];
    const float* t2h_W   = (const float*)d_in[16];
    const float* t2h_b   = (const float*)d_in[17];

    float* out      = (float*)d_out;
    float* recon    = out;                                  // [B,O]
    float* onehot   = out + (size_t)B_ * O_;                // [B,L,D]
    float* logits   = onehot + (size_t)B_ * L_ * D_;        // [B,L,D]
    float* messages = logits + (size_t)B_ * L_ * D_;        // [B,L]

    float* ws    = (float*)d_ws;
    float* ecx   = ws;                                      // [B,H]
    float* dcx   = ecx + (size_t)B_ * H_;                   // [B,H]
    float* emb   = dcx + (size_t)B_ * H_;                   // [D,H]
    float* P_enc = emb + (size_t)D_ * H_;                   // [D,4H]
    float* P_dec = P_enc + (size_t)D_ * H4_;                // [D,4H]
    float* hxf   = P_dec + (size_t)D_ * H4_;                // [B,H]
    float* pbest = hxf + (size_t)B_ * H_;                   // [B,16]
    int*   pidx  = (int*)(pbest + (size_t)B_ * 16);         // [B,16]
    _Float16* fb   = (_Float16*)(pidx + (size_t)B_ * 16);
    _Float16* ehA1 = fb;  fb += (size_t)B_ * H_;
    _Float16* ehA2 = fb;  fb += (size_t)B_ * H_;
    _Float16* ehB1 = fb;  fb += (size_t)B_ * H_;
    _Float16* ehB2 = fb;  fb += (size_t)B_ * H_;
    _Float16* dhA1 = fb;  fb += (size_t)B_ * H_;
    _Float16* dhA2 = fb;  fb += (size_t)B_ * H_;
    _Float16* dhB1 = fb;  fb += (size_t)B_ * H_;
    _Float16* dhB2 = fb;  fb += (size_t)B_ * H_;
    _Float16* encW1 = fb; fb += (size_t)H4_ * H_;   // Whh splits
    _Float16* encW2 = fb; fb += (size_t)H4_ * H_;
    _Float16* decW1 = fb; fb += (size_t)H4_ * H_;
    _Float16* decW2 = fb; fb += (size_t)H4_ * H_;
    _Float16* h2t1  = fb; fb += (size_t)D_ * H_;
    _Float16* h2t2  = fb; fb += (size_t)D_ * H_;
    _Float16* embs1 = fb; fb += (size_t)D_ * H_;
    _Float16* embs2 = fb; fb += (size_t)D_ * H_;
    _Float16* eWih1 = fb; fb += (size_t)H4_ * H_;   // Wih splits (for P)
    _Float16* eWih2 = fb; fb += (size_t)H4_ * H_;
    _Float16* dWih1 = fb; fb += (size_t)H4_ * H_;
    _Float16* dWih2 = fb;

    const dim3 blk256(256);

    (void)hipMemsetAsync(ehA1, 0, (size_t)B_ * H_ * 4, stream);   // ehA1+ehA2
    (void)hipMemsetAsync(dhA1, 0, (size_t)B_ * H_ * 4, stream);   // dhA1+dhA2
    (void)hipMemsetAsync(dcx, 0, (size_t)B_ * H_ * sizeof(float), stream);
    (void)hipMemsetAsync(onehot, 0, (size_t)B_ * L_ * D_ * sizeof(float), stream);

    // weight splits (one-time)
    split_f16<<<dim3((H4_ * H_ / 4) / 256), blk256, 0, stream>>>(
        enc_Whh, encW1, encW2, H4_ * H_ / 4);
    split_f16<<<dim3((H4_ * H_ / 4) / 256), blk256, 0, stream>>>(
        dec_Whh, decW1, decW2, H4_ * H_ / 4);
    split_f16<<<dim3((D_ * H_ / 4) / 256), blk256, 0, stream>>>(
        h2t_W, h2t1, h2t2, D_ * H_ / 4);
    split_f16<<<dim3((H4_ * H_ / 4) / 256), blk256, 0, stream>>>(
        enc_Wih, eWih1, eWih2, H4_ * H_ / 4);
    split_f16<<<dim3((H4_ * H_ / 4) / 256), blk256, 0, stream>>>(
        dec_Wih, dWih1, dWih2, H4_ * H_ / 4);

    // cx0 (encoder initial cell state) = x @ in_W^T + in_b  (fp32)
    gemm_atb<<<dim3(H_ / 64, B_ / 64), blk256, 0, stream>>>(
        x, in_W, in_b, ecx, H_, nullptr, 0, B_, H_, I_);

    // one-hot decode table and the two precomputed gather tables (MFMA)
    build_emb<<<dim3((D_ * H_) / 256), blk256, 0, stream>>>(t2h_W, t2h_b, emb);
    split_f16<<<dim3((D_ * H_ / 4) / 256), blk256, 0, stream>>>(
        emb, embs1, embs2, D_ * H_ / 4);
    gemm_mfma_atb<<<dim3(H4_ / 64, D_ / 64), blk256, 0, stream>>>(
        embs1, embs2, eWih1, eWih2, P_enc, H4_, H_);
    gemm_mfma_atb<<<dim3(H4_ / 64, D_ / 64), blk256, 0, stream>>>(
        embs1, embs2, dWih1, dWih2, P_dec, H4_, H_);

    _Float16* e1[2] = {ehA1, ehB1};
    _Float16* e2[2] = {ehA2, ehB2};
    _Float16* d1[2] = {dhA1, dhB1};
    _Float16* d2[2] = {dhA2, dhB2};

    // -------- fused encoder + (lagged) decoder --------
    for (int l = 0; l < L_; ++l) {
        int ein = l & 1, eo = ein ^ 1;
        int din = (l - 1) & 1, do_ = din ^ 1;     // dec step l-1 (l>=1)
        lstm_fused<<<dim3(H_ / 32, B_ / 64, l ? 2 : 1), blk256, 0, stream>>>(
            e1[ein], e2[ein], ecx, encW1, encW2, P_enc, enc_bih, enc_bhh,
            e1[eo], e2[eo],
            l ? d1[din] : nullptr, l ? d2[din] : nullptr, dcx,
            decW1, decW2, P_dec, dec_bih, dec_bhh,
            l ? d1[do_] : nullptr, l ? d2[do_] : nullptr,
            nullptr, pbest, pidx, l ? 1 : 0,
            onehot, messages, l - 1, l ? 3 : 1);
        gemm_pre_fused<<<dim3(D_ / 64, B_ / 64), blk256, 0, stream>>>(
            e1[eo], e2[eo], h2t1, h2t2, h2t_b,
            logits + (size_t)l * D_, L_ * D_,
            gumbel + (size_t)l * B_ * D_, pbest, pidx);
    }

    // -------- decoder tail: step 31 (consumes partials of step 31) --------
    lstm_fused<<<dim3(H_ / 32, B_ / 64, 1), blk256, 0, stream>>>(
        nullptr, nullptr, ecx, encW1, encW2, P_enc, enc_bih, enc_bhh,
        nullptr, nullptr,
        d1[1], d2[1], dcx, decW1, decW2, P_dec, dec_bih, dec_bhh,
        d1[0], d2[0],
        hxf, pbest, pidx, 1,
        onehot, messages, L_ - 1, 2);

    // recon = hx_final @ out_W^T + out_b  (fp32)
    gemm_atb<<<dim3(O_ / 64, B_ / 64), blk256, 0, stream>>>(
        hxf, out_W, out_b, recon, O_, nullptr, 0, B_, O_, H_);
}